// Round 1
// baseline (340.586 us; speedup 1.0000x reference)
//
#include <hip/hip_runtime.h>
#include <math.h>

// ---------------------------------------------------------------------------
// TitansMemoryModule fused update, MI355X (gfx950)
//   retrieved = k @ W^T          (32768x512 @ 512x512^T)  -> bf16 MFMA
//   loss      = mean((retrieved - v)^2)
//   gates     = sigmoid(concat(mean(k,0), mean(v,0)) @ gate_w^T + gate_b)
//   grad      = 2/(B*vd) * diff^T @ k                     -> bf16 MFMA, split-K
//   new_momentum = clipF(eta*S - 0.005*theta*clip(grad,-1,1))
//   new_weight   = clipF((1-alpha)*W + new_momentum)
// Output layout (flat f32): retrieved[16777216], loss[1], new_weight[262144],
//   new_momentum[262144], alpha, eta, theta
// ---------------------------------------------------------------------------

typedef __bf16 bf16x8 __attribute__((ext_vector_type(8)));
typedef float f32x4 __attribute__((ext_vector_type(4)));
typedef float float4_t __attribute__((ext_vector_type(4)));
typedef unsigned short ushort4_t __attribute__((ext_vector_type(4)));
typedef unsigned short ushort8_t __attribute__((ext_vector_type(8)));

#define OUT_LOSS   16777216
#define OUT_W      16777217
#define OUT_MOM    17039361
#define OUT_ALPHA  17301505

// ws layout (bytes):
//   0        grad accum   (512*512 f32 = 1 MB)        [zeroed each call]
//   1048576  colsum_k     (512 f32)                   [zeroed]
//   1050624  colsum_v     (512 f32)                   [zeroed]
//   1052672  scal[6]: 0=loss_acc 1=normM_acc 2=normW_acc 3=alpha 4=eta 5=theta
//   1056768  diff16       (32768*512 bf16 = 32 MB)
//   34611200 k16          (32 MB)
//   68165632 m_raw        (1 MB)
//   69214208 w_raw        (1 MB)   total ~70.3 MB

__device__ __forceinline__ unsigned short f2bf(float f) {
  union { float f; unsigned int u; } c; c.f = f;
  unsigned int u = c.u;
  u += 0x7fffu + ((u >> 16) & 1u);   // round-to-nearest-even
  return (unsigned short)(u >> 16);
}

// ---------------------------------------------------------------------------
// K2: retrieved = k @ W^T, plus diff16/k16 staging, colsums, loss partial.
// 128x128 tile, BK=64, 4 waves (2x2 of 64x64), mfma_f32_16x16x32_bf16.
// ---------------------------------------------------------------------------
__global__ __launch_bounds__(256) void k2_gemm_retr(
    const float* __restrict__ Kp, const float* __restrict__ Vp,
    const float* __restrict__ Wp, float* __restrict__ outp,
    unsigned short* __restrict__ diff16, unsigned short* __restrict__ k16,
    float* __restrict__ colk, float* __restrict__ colv, float* scal)
{
  __shared__ __align__(16) unsigned short As[128][72];  // stride 144B: 16B aligned, 2-way banks
  __shared__ __align__(16) unsigned short Bs[128][72];
  const int t = threadIdx.x;
  const int lane = t & 63;
  const int wv = t >> 6;
  const int bid = blockIdx.x;
  const int row0 = (bid >> 2) << 7;   // 256 row tiles
  const int vdTile = bid & 3;
  const int vd0 = vdTile << 7;

  f32x4 acc[4][4];
#pragma unroll
  for (int m = 0; m < 4; ++m)
#pragma unroll
    for (int n = 0; n < 4; ++n)
      acc[m][n] = (f32x4){0.f, 0.f, 0.f, 0.f};

  const int sr = t >> 4;          // staging row 0..15 per pass
  const int sc = (t & 15) << 2;   // staging col (float4)
  const int wr = (wv >> 1) << 6;
  const int wc = (wv & 1) << 6;
  const int fr = lane & 15;
  const int fq = lane >> 4;

  for (int kk0 = 0; kk0 < 512; kk0 += 64) {
    float kcs[4] = {0.f, 0.f, 0.f, 0.f};
#pragma unroll
    for (int p = 0; p < 8; ++p) {
      const int r = (p << 4) + sr;
      const float4_t av = *reinterpret_cast<const float4_t*>(
          &Kp[(size_t)(row0 + r) * 512 + kk0 + sc]);
      ushort4_t ah;
      ah.x = f2bf(av.x); ah.y = f2bf(av.y); ah.z = f2bf(av.z); ah.w = f2bf(av.w);
      *reinterpret_cast<ushort4_t*>(&As[r][sc]) = ah;
      const float4_t bv = *reinterpret_cast<const float4_t*>(
          &Wp[(size_t)(vd0 + r) * 512 + kk0 + sc]);
      ushort4_t bh;
      bh.x = f2bf(bv.x); bh.y = f2bf(bv.y); bh.z = f2bf(bv.z); bh.w = f2bf(bv.w);
      *reinterpret_cast<ushort4_t*>(&Bs[r][sc]) = bh;
      if (vdTile == 0) {   // block-uniform branch
        *reinterpret_cast<ushort4_t*>(&k16[(size_t)(row0 + r) * 512 + kk0 + sc]) = ah;
        kcs[0] += av.x; kcs[1] += av.y; kcs[2] += av.z; kcs[3] += av.w;
      }
    }
    if (vdTile == 0) {    // k column sums (disjoint coverage by vdTile==0 blocks)
#pragma unroll
      for (int j = 0; j < 4; ++j) {
        kcs[j] += __shfl_xor(kcs[j], 16);
        kcs[j] += __shfl_xor(kcs[j], 32);
      }
      if (fq == 0) {
#pragma unroll
        for (int j = 0; j < 4; ++j)
          atomicAdd(&colk[kk0 + (fr << 2) + j], kcs[j]);
      }
    }
    __syncthreads();
#pragma unroll
    for (int kk = 0; kk < 64; kk += 32) {
      const int co = kk + (fq << 3);
      bf16x8 af[4], bfv[4];
#pragma unroll
      for (int m = 0; m < 4; ++m)
        af[m] = *reinterpret_cast<const bf16x8*>(&As[wr + (m << 4) + fr][co]);
#pragma unroll
      for (int n = 0; n < 4; ++n)
        bfv[n] = *reinterpret_cast<const bf16x8*>(&Bs[wc + (n << 4) + fr][co]);
#pragma unroll
      for (int m = 0; m < 4; ++m)
#pragma unroll
        for (int n = 0; n < 4; ++n)
          acc[m][n] = __builtin_amdgcn_mfma_f32_16x16x32_bf16(af[m], bfv[n], acc[m][n], 0, 0, 0);
    }
    __syncthreads();
  }

  // epilogue: write retrieved, diff16(bf16); accumulate loss + v colsums
  float lsum = 0.f;
  float vcs[4] = {0.f, 0.f, 0.f, 0.f};
#pragma unroll
  for (int m = 0; m < 4; ++m) {
#pragma unroll
    for (int n = 0; n < 4; ++n) {
#pragma unroll
      for (int i = 0; i < 4; ++i) {
        const int gr = row0 + wr + (m << 4) + (fq << 2) + i;   // D row = A-row
        const int gc = vd0 + wc + (n << 4) + fr;               // D col = B-row
        const size_t oi = (size_t)gr * 512 + gc;
        const float rv = acc[m][n][i];
        outp[oi] = rv;
        const float vv = Vp[oi];
        const float d = rv - vv;
        lsum += d * d;
        vcs[n] += vv;
        diff16[oi] = f2bf(d);
      }
    }
  }
#pragma unroll
  for (int o = 32; o; o >>= 1) lsum += __shfl_xor(lsum, o);
  if (lane == 0) atomicAdd(&scal[0], lsum);
#pragma unroll
  for (int n = 0; n < 4; ++n) {
    vcs[n] += __shfl_xor(vcs[n], 16);
    vcs[n] += __shfl_xor(vcs[n], 32);
  }
  if (fq == 0) {
#pragma unroll
    for (int n = 0; n < 4; ++n)
      atomicAdd(&colv[vd0 + wc + (n << 4) + fr], vcs[n]);
  }
}

// ---------------------------------------------------------------------------
// K3: grad_raw += diff^T @ k  (split-K, bf16 MFMA, transposed LDS staging)
// 128x128 output tile, 32 K-chunks of 1024 rows, grid 512 blocks.
// Block swizzle groups all 16 tiles of one K-chunk onto one XCD (bid%8=XCD).
// LDS [col][r] with XOR swizzle on r-block to kill 16-way write conflicts.
// ---------------------------------------------------------------------------
__global__ __launch_bounds__(256) void k3_grad(
    const unsigned short* __restrict__ diff16,
    const unsigned short* __restrict__ k16,
    float* __restrict__ grad)
{
  __shared__ __align__(16) unsigned short At[2][128][40];  // [buf][vd][r(32)+pad]
  __shared__ __align__(16) unsigned short Bt[2][128][40];  // [buf][kd][r]
  const int t = threadIdx.x;
  const int lane = t & 63;
  const int wv = t >> 6;
  const int b = blockIdx.x;
  const int x = b & 7;            // XCD slot
  const int q = b >> 3;
  const int tile = q & 15;
  const int kc = ((q >> 4) << 3) | x;   // 0..31; all 16 tiles of kc share XCD
  const int vd0 = (tile & 3) << 7;
  const int kd0 = (tile >> 2) << 7;
  const size_t r0 = (size_t)kc << 10;   // 1024 rows per chunk

  f32x4 acc[4][4];
#pragma unroll
  for (int m = 0; m < 4; ++m)
#pragma unroll
    for (int n = 0; n < 4; ++n)
      acc[m][n] = (f32x4){0.f, 0.f, 0.f, 0.f};

  const int dr = t >> 3;          // 0..31 source row
  const int c0 = (t & 7) << 4;    // 16 cols per thread
  const int wr = (wv >> 1) << 6;
  const int wc = (wv & 1) << 6;
  const int fr = lane & 15;
  const int fq = lane >> 4;

  int cur = 0;
  for (int rr = 0; rr < 1024; rr += 32) {
    const size_t rowoff = (r0 + rr + dr) << 9;   // *512
    const ushort8_t a0 = *reinterpret_cast<const ushort8_t*>(&diff16[rowoff + vd0 + c0]);
    const ushort8_t a1 = *reinterpret_cast<const ushort8_t*>(&diff16[rowoff + vd0 + c0 + 8]);
    const ushort8_t b0 = *reinterpret_cast<const ushort8_t*>(&k16[rowoff + kd0 + c0]);
    const ushort8_t b1 = *reinterpret_cast<const ushort8_t*>(&k16[rowoff + kd0 + c0 + 8]);
    const int swz = ((c0 >> 4) & 3) << 3;   // same for c0..c0+15
#pragma unroll
    for (int j = 0; j < 8; ++j) {
      const int drs = dr ^ swz;
      At[cur][c0 + j][drs] = a0[j];
      At[cur][c0 + 8 + j][drs] = a1[j];
      Bt[cur][c0 + j][drs] = b0[j];
      Bt[cur][c0 + 8 + j][drs] = b1[j];
    }
    __syncthreads();
    bf16x8 af[4], bfv[4];
#pragma unroll
    for (int m = 0; m < 4; ++m) {
      const int rA = wr + (m << 4) + fr;
      af[m] = *reinterpret_cast<const bf16x8*>(&At[cur][rA][(fq ^ ((rA >> 4) & 3)) << 3]);
    }
#pragma unroll
    for (int n = 0; n < 4; ++n) {
      const int rB = wc + (n << 4) + fr;
      bfv[n] = *reinterpret_cast<const bf16x8*>(&Bt[cur][rB][(fq ^ ((rB >> 4) & 3)) << 3]);
    }
#pragma unroll
    for (int m = 0; m < 4; ++m)
#pragma unroll
      for (int n = 0; n < 4; ++n)
        acc[m][n] = __builtin_amdgcn_mfma_f32_16x16x32_bf16(af[m], bfv[n], acc[m][n], 0, 0, 0);
    cur ^= 1;
  }
#pragma unroll
  for (int m = 0; m < 4; ++m)
#pragma unroll
    for (int n = 0; n < 4; ++n)
#pragma unroll
      for (int i = 0; i < 4; ++i)
        atomicAdd(&grad[(size_t)(vd0 + wr + (m << 4) + (fq << 2) + i) * 512
                        + kd0 + wc + (n << 4) + fr], acc[m][n][i]);
}

// ---------------------------------------------------------------------------
// C1: gates + loss finalize (1 block)
// ---------------------------------------------------------------------------
__global__ __launch_bounds__(256) void c1_gates(
    const float* __restrict__ gw, const float* __restrict__ gb,
    const float* __restrict__ colk, const float* __restrict__ colv,
    float* scal, float* __restrict__ outp)
{
  __shared__ float red[3][4];
  const int t = threadIdx.x;
  float p[3] = {0.f, 0.f, 0.f};
  for (int j = t; j < 1024; j += 256) {
    const float kv = (j < 512 ? colk[j] : colv[j - 512]) * (1.0f / 32768.0f);
    p[0] += kv * gw[j];
    p[1] += kv * gw[1024 + j];
    p[2] += kv * gw[2048 + j];
  }
#pragma unroll
  for (int g = 0; g < 3; ++g)
#pragma unroll
    for (int o = 32; o; o >>= 1) p[g] += __shfl_xor(p[g], o);
  const int lane = t & 63, wv = t >> 6;
  if (lane == 0) { red[0][wv] = p[0]; red[1][wv] = p[1]; red[2][wv] = p[2]; }
  __syncthreads();
  if (t == 0) {
    const float s0 = red[0][0] + red[0][1] + red[0][2] + red[0][3] + gb[0];
    const float s1 = red[1][0] + red[1][1] + red[1][2] + red[1][3] + gb[1];
    const float s2 = red[2][0] + red[2][1] + red[2][2] + red[2][3] + gb[2];
    const float alpha = 1.0f / (1.0f + expf(-s0));
    const float eta   = 1.0f / (1.0f + expf(-s1));
    const float theta = 1.0f / (1.0f + expf(-s2));
    scal[3] = alpha; scal[4] = eta; scal[5] = theta;
    outp[OUT_LOSS] = scal[0] * (1.0f / 16777216.0f);
    outp[OUT_ALPHA]     = alpha;
    outp[OUT_ALPHA + 1] = eta;
    outp[OUT_ALPHA + 2] = theta;
  }
}

__device__ __forceinline__ void block_atomic_sumsq(float sq, float* target) {
  __shared__ float red[4];
#pragma unroll
  for (int o = 32; o; o >>= 1) sq += __shfl_xor(sq, o);
  if ((threadIdx.x & 63) == 0) red[threadIdx.x >> 6] = sq;
  __syncthreads();
  if (threadIdx.x == 0) atomicAdd(target, red[0] + red[1] + red[2] + red[3]);
}

// C2: m_raw = eta*S - 0.005*theta*clip(grad*scale); accumulate ||m||^2
__global__ __launch_bounds__(256) void c2_mom(
    const float* __restrict__ grad, const float* __restrict__ S,
    float* scal, float* __restrict__ m_raw)
{
  const float eta = scal[4];
  const float cth = 0.005f * scal[5];
  float sq = 0.f;
  for (int i = blockIdx.x * 256 + threadIdx.x; i < 262144; i += 256 * 256) {
    float g = grad[i] * (2.0f / 16777216.0f);
    g = fminf(1.0f, fmaxf(-1.0f, g));
    const float m = eta * S[i] - cth * g;
    m_raw[i] = m;
    sq += m * m;
  }
  block_atomic_sumsq(sq, &scal[1]);
}

// C3: clip momentum -> out; w_raw = (1-alpha)*W + m; accumulate ||w||^2
__global__ __launch_bounds__(256) void c3_wt(
    const float* __restrict__ m_raw, const float* __restrict__ memw,
    float* scal, float* __restrict__ w_raw, float* __restrict__ outp)
{
  const float nm = sqrtf(scal[1]);
  const float sm = nm > 5.0f ? 5.0f / (nm + 1e-8f) : 1.0f;
  const float oma = 1.0f - scal[3];
  float sq = 0.f;
  for (int i = blockIdx.x * 256 + threadIdx.x; i < 262144; i += 256 * 256) {
    const float m = m_raw[i] * sm;
    outp[OUT_MOM + i] = m;
    const float w = oma * memw[i] + m;
    w_raw[i] = w;
    sq += w * w;
  }
  block_atomic_sumsq(sq, &scal[2]);
}

// C4: clip weight -> out
__global__ __launch_bounds__(256) void c4_wt(
    const float* __restrict__ w_raw, const float* scal, float* __restrict__ outp)
{
  const float nw = sqrtf(scal[2]);
  const float sw = nw > 5.0f ? 5.0f / (nw + 1e-8f) : 1.0f;
  for (int i = blockIdx.x * 256 + threadIdx.x; i < 262144; i += 256 * 256)
    outp[OUT_W + i] = w_raw[i] * sw;
}

// ---------------------------------------------------------------------------
extern "C" void kernel_launch(void* const* d_in, const int* in_sizes, int n_in,
                              void* d_out, int out_size, void* d_ws, size_t ws_size,
                              hipStream_t stream)
{
  const float* Kp = (const float*)d_in[0];
  const float* Vp = (const float*)d_in[1];
  const float* Wp = (const float*)d_in[2];
  const float* GW = (const float*)d_in[3];
  const float* GB = (const float*)d_in[4];
  const float* Sp = (const float*)d_in[5];
  float* outp = (float*)d_out;
  char* ws = (char*)d_ws;

  float* grad = (float*)ws;
  float* colk = (float*)(ws + 1048576);
  float* colv = (float*)(ws + 1050624);
  float* scal = (float*)(ws + 1052672);
  unsigned short* diff16 = (unsigned short*)(ws + 1056768);
  unsigned short* k16    = (unsigned short*)(ws + 1056768 + 33554432);
  float* m_raw = (float*)(ws + 1056768 + 2 * 33554432);
  float* w_raw = (float*)(ws + 1056768 + 2 * 33554432 + 1048576);

  // zero accumulators (grad + colsums + scal)
  hipMemsetAsync(d_ws, 0, 1056768, stream);

  k2_gemm_retr<<<1024, 256, 0, stream>>>(Kp, Vp, Wp, outp, diff16, k16, colk, colv, scal);
  k3_grad<<<512, 256, 0, stream>>>(diff16, k16, grad);
  c1_gates<<<1, 256, 0, stream>>>(GW, GB, colk, colv, scal, outp);
  c2_mom<<<256, 256, 0, stream>>>(grad, Sp, scal, m_raw);
  c3_wt<<<256, 256, 0, stream>>>(m_raw, Wp, scal, w_raw, outp);
  c4_wt<<<256, 256, 0, stream>>>(w_raw, scal, outp);
}

// Round 2
// 183.793 us; speedup vs baseline: 1.8531x; 1.8531x over previous
//
#include <hip/hip_runtime.h>
#include <math.h>

// ---------------------------------------------------------------------------
// TitansMemoryModule fused update, MI355X (gfx950) — round 2
//   K1: f32->bf16 convert of K,W + colk partials (streaming)
//   K2: retrieved = k16 @ w16^T via global_load_lds m97-pattern bf16 MFMA,
//       fused epilogue: V read, diff16 write, loss/colv partials
//   K3: grad = diff^T @ k (split-K bf16 MFMA, XCD-grouped, atomics into f32)
//   C1a/C1b: partial reductions + gates; C2-C4: momentum/weight + norm clips
// Output layout (flat f32): retrieved[16777216], loss[1], new_weight[262144],
//   new_momentum[262144], alpha, eta, theta
// ---------------------------------------------------------------------------

typedef __bf16 bf16x8 __attribute__((ext_vector_type(8)));
typedef float f32x4 __attribute__((ext_vector_type(4)));
typedef float float4_t __attribute__((ext_vector_type(4)));
typedef unsigned short ushort4_t __attribute__((ext_vector_type(4)));
typedef unsigned short ushort8_t __attribute__((ext_vector_type(8)));

#define OUT_LOSS   16777216
#define OUT_W      16777217
#define OUT_MOM    17039361
#define OUT_ALPHA  17301505

// ws layout (bytes) — total 70,259,776 (< round-1's proven 70,262,784)
#define OFF_GRAD   0u           // 1 MB f32 grad accum           [memset 0]
#define OFF_CKP    1048576u     // colk partials [512][512] f32 = 1 MB
#define OFF_CVP    2097152u     // colv partials [256][512] f32 = 512 KB
#define OFF_LOSSP  2621440u     // loss partials [256] f32       [memset 0]
#define OFF_COLK   2622464u     // 512 f32
#define OFF_COLV   2624512u     // 512 f32
#define OFF_SCAL   2626560u     // 16 f32: 1=||m||^2 2=||w||^2 3=a 4=e 5=t  [memset 0]
#define OFF_K16    2626624u     // 32 MB bf16 K
#define OFF_W16    36181056u    // 512 KB bf16 W
#define OFF_DIFF   36705344u    // 32 MB bf16 diff
#define OFF_MRAW   OFF_K16      // aliases k16 (dead after K3)
#define OFF_WRAW   (OFF_K16 + 1048576u)

__device__ __forceinline__ unsigned short f2bf(float f) {
  union { float f; unsigned int u; } c; c.f = f;
  unsigned int u = c.u;
  u += 0x7fffu + ((u >> 16) & 1u);   // round-to-nearest-even
  return (unsigned short)(u >> 16);
}

__device__ __forceinline__ void gload_lds16(const unsigned short* g, unsigned short* l) {
  __builtin_amdgcn_global_load_lds(
      (const __attribute__((address_space(1))) unsigned int*)g,
      (__attribute__((address_space(3))) unsigned int*)l, 16, 0, 0);
}

// ---------------------------------------------------------------------------
// K1: convert K (bid<512, 64 rows each) and W (bid 512..527, 32 rows each)
// to bf16; per-block column-sum partials for K (no atomics).
// ---------------------------------------------------------------------------
__global__ __launch_bounds__(256) void k1_convert(
    const float* __restrict__ Kp, const float* __restrict__ Wp,
    unsigned short* __restrict__ k16, unsigned short* __restrict__ w16,
    float* __restrict__ colk_part)
{
  __shared__ float cp[512];
  const int t = threadIdx.x;
  const int cg = t & 127;          // column group of 4
  const int g = t >> 7;            // row-phase 0/1
  const int b = blockIdx.x;
  if (b < 512) {
    const int r0 = b << 6;
    float p0 = 0.f, p1 = 0.f, p2 = 0.f, p3 = 0.f;
#pragma unroll 4
    for (int rr = g; rr < 64; rr += 2) {
      const size_t off = (size_t)(r0 + rr) * 512 + (cg << 2);
      const float4_t v = *reinterpret_cast<const float4_t*>(&Kp[off]);
      ushort4_t h;
      h.x = f2bf(v.x); h.y = f2bf(v.y); h.z = f2bf(v.z); h.w = f2bf(v.w);
      *reinterpret_cast<ushort4_t*>(&k16[off]) = h;
      p0 += v.x; p1 += v.y; p2 += v.z; p3 += v.w;
    }
    if (g == 1) {
      cp[(cg << 2) + 0] = p0; cp[(cg << 2) + 1] = p1;
      cp[(cg << 2) + 2] = p2; cp[(cg << 2) + 3] = p3;
    }
    __syncthreads();
    if (g == 0) {
      colk_part[(size_t)b * 512 + (cg << 2) + 0] = p0 + cp[(cg << 2) + 0];
      colk_part[(size_t)b * 512 + (cg << 2) + 1] = p1 + cp[(cg << 2) + 1];
      colk_part[(size_t)b * 512 + (cg << 2) + 2] = p2 + cp[(cg << 2) + 2];
      colk_part[(size_t)b * 512 + (cg << 2) + 3] = p3 + cp[(cg << 2) + 3];
    }
  } else {
    const int r0 = (b - 512) << 5;
#pragma unroll 4
    for (int rr = g; rr < 32; rr += 2) {
      const size_t off = (size_t)(r0 + rr) * 512 + (cg << 2);
      const float4_t v = *reinterpret_cast<const float4_t*>(&Wp[off]);
      ushort4_t h;
      h.x = f2bf(v.x); h.y = f2bf(v.y); h.z = f2bf(v.z); h.w = f2bf(v.w);
      *reinterpret_cast<ushort4_t*>(&w16[off]) = h;
    }
  }
}

// ---------------------------------------------------------------------------
// K2: retrieved = k16 @ w16^T.  m97 structure: 128x128 tile, BK=64, 4 waves,
// global_load_lds width 16, linear LDS [128][64]. XCD-grouped tile swizzle.
// Fused epilogue: V read, diff16 write, colv/loss partials.
// ---------------------------------------------------------------------------
__global__ __launch_bounds__(256) void k2_gemm(
    const unsigned short* __restrict__ k16, const unsigned short* __restrict__ w16,
    const float* __restrict__ Vp, float* __restrict__ outp,
    unsigned short* __restrict__ diff16,
    float* __restrict__ colv_part, float* __restrict__ loss_part)
{
  __shared__ __align__(16) unsigned short As[8192];   // [128][64] bf16, linear
  __shared__ __align__(16) unsigned short Bs[8192];
  __shared__ float redc[256];
  __shared__ float redl[4];

  const int t = threadIdx.x, lane = t & 63, wv = t >> 6;
  // XCD-grouped swizzle: xcd = bid&7 gets 128 contiguous tiles -> the 4
  // vd-tiles of each rowtile share one XCD's L2 (k16 rowtile fetched once).
  const int tile = (blockIdx.x & 7) * 128 + (blockIdx.x >> 3);
  const int rt = tile >> 2, vt = tile & 3;
  const int row0 = rt << 7, vd0 = vt << 7;

  f32x4 acc[4][4];
#pragma unroll
  for (int m = 0; m < 4; ++m)
#pragma unroll
    for (int n = 0; n < 4; ++n)
      acc[m][n] = (f32x4){0.f, 0.f, 0.f, 0.f};

  // staging: wave wv, pass i covers rows i*32 + wv*8 + (lane>>3), 16B/lane
  const int srow = (wv << 3) + (lane >> 3);
  const int scol = (lane & 7) << 3;
  const unsigned short* pA = k16 + (size_t)(row0 + srow) * 512 + scol;
  const unsigned short* pB = w16 + (size_t)(vd0 + srow) * 512 + scol;
  unsigned short* lA = &As[wv << 9];   // wv*1024 bytes
  unsigned short* lB = &Bs[wv << 9];

  const int fr = lane & 15, fq = lane >> 4;
  const int wr = (wv >> 1) << 6, wc = (wv & 1) << 6;

  for (int kk0 = 0; kk0 < 512; kk0 += 64) {
#pragma unroll
    for (int i = 0; i < 4; ++i) {
      gload_lds16(pA + (i << 14) + kk0, lA + (i << 11));   // i*32 rows, 4KB LDS
      gload_lds16(pB + (i << 14) + kk0, lB + (i << 11));
    }
    __syncthreads();   // drains vmcnt(0): tile resident
#pragma unroll
    for (int kk = 0; kk < 64; kk += 32) {
      const int co = kk + (fq << 3);
      bf16x8 af[4], bfv[4];
#pragma unroll
      for (int m = 0; m < 4; ++m)
        af[m] = *reinterpret_cast<const bf16x8*>(&As[((wr + (m << 4) + fr) << 6) + co]);
#pragma unroll
      for (int n = 0; n < 4; ++n)
        bfv[n] = *reinterpret_cast<const bf16x8*>(&Bs[((wc + (n << 4) + fr) << 6) + co]);
#pragma unroll
      for (int m = 0; m < 4; ++m)
#pragma unroll
        for (int n = 0; n < 4; ++n)
          acc[m][n] = __builtin_amdgcn_mfma_f32_16x16x32_bf16(af[m], bfv[n], acc[m][n], 0, 0, 0);
    }
    __syncthreads();
  }

  // epilogue: write retrieved + diff16; loss & colv partials (no hot atomics)
  float lsum = 0.f;
  float vcs[4] = {0.f, 0.f, 0.f, 0.f};
#pragma unroll
  for (int m = 0; m < 4; ++m) {
#pragma unroll
    for (int n = 0; n < 4; ++n) {
#pragma unroll
      for (int i = 0; i < 4; ++i) {
        const int gr = row0 + wr + (m << 4) + (fq << 2) + i;
        const int gc = vd0 + wc + (n << 4) + fr;
        const size_t oi = (size_t)gr * 512 + gc;
        const float rv = acc[m][n][i];
        outp[oi] = rv;
        const float vv = Vp[oi];
        const float d = rv - vv;
        lsum += d * d;
        vcs[n] += vv;
        diff16[oi] = f2bf(d);
      }
    }
  }
#pragma unroll
  for (int o = 32; o; o >>= 1) lsum += __shfl_xor(lsum, o);
  if (lane == 0) redl[wv] = lsum;
#pragma unroll
  for (int n = 0; n < 4; ++n) {
    vcs[n] += __shfl_xor(vcs[n], 16);
    vcs[n] += __shfl_xor(vcs[n], 32);
  }
  if (fq == 0) {
#pragma unroll
    for (int n = 0; n < 4; ++n)
      redc[(wv << 6) + (n << 4) + fr] = vcs[n];
  }
  __syncthreads();
  if (t < 128) {   // column t of this block's 128-col slab
    const int side = t >> 6, lc = t & 63;
    colv_part[(size_t)rt * 512 + vd0 + t] =
        redc[side * 64 + lc] + redc[(side + 2) * 64 + lc];
  }
  if (t == 0)
    atomicAdd(&loss_part[rt], redl[0] + redl[1] + redl[2] + redl[3]);  // 4-way only
}

// ---------------------------------------------------------------------------
// K3: grad += diff^T @ k  (split-K, bf16 MFMA, transposed LDS staging,
// XCD-grouped so each 1024-row chunk's 16 tiles share an L2). Unchanged.
// ---------------------------------------------------------------------------
__global__ __launch_bounds__(256) void k3_grad(
    const unsigned short* __restrict__ diff16,
    const unsigned short* __restrict__ k16,
    float* __restrict__ grad)
{
  __shared__ __align__(16) unsigned short At[2][128][40];
  __shared__ __align__(16) unsigned short Bt[2][128][40];
  const int t = threadIdx.x;
  const int lane = t & 63;
  const int wv = t >> 6;
  const int b = blockIdx.x;
  const int x = b & 7;
  const int q = b >> 3;
  const int tile = q & 15;
  const int kc = ((q >> 4) << 3) | x;
  const int vd0 = (tile & 3) << 7;
  const int kd0 = (tile >> 2) << 7;
  const size_t r0 = (size_t)kc << 10;

  f32x4 acc[4][4];
#pragma unroll
  for (int m = 0; m < 4; ++m)
#pragma unroll
    for (int n = 0; n < 4; ++n)
      acc[m][n] = (f32x4){0.f, 0.f, 0.f, 0.f};

  const int dr = t >> 3;
  const int c0 = (t & 7) << 4;
  const int wr = (wv >> 1) << 6;
  const int wc = (wv & 1) << 6;
  const int fr = lane & 15;
  const int fq = lane >> 4;

  int cur = 0;
  for (int rr = 0; rr < 1024; rr += 32) {
    const size_t rowoff = (r0 + rr + dr) << 9;
    const ushort8_t a0 = *reinterpret_cast<const ushort8_t*>(&diff16[rowoff + vd0 + c0]);
    const ushort8_t a1 = *reinterpret_cast<const ushort8_t*>(&diff16[rowoff + vd0 + c0 + 8]);
    const ushort8_t b0 = *reinterpret_cast<const ushort8_t*>(&k16[rowoff + kd0 + c0]);
    const ushort8_t b1 = *reinterpret_cast<const ushort8_t*>(&k16[rowoff + kd0 + c0 + 8]);
    const int swz = ((c0 >> 4) & 3) << 3;
#pragma unroll
    for (int j = 0; j < 8; ++j) {
      const int drs = dr ^ swz;
      At[cur][c0 + j][drs] = a0[j];
      At[cur][c0 + 8 + j][drs] = a1[j];
      Bt[cur][c0 + j][drs] = b0[j];
      Bt[cur][c0 + 8 + j][drs] = b1[j];
    }
    __syncthreads();
    bf16x8 af[4], bfv[4];
#pragma unroll
    for (int m = 0; m < 4; ++m) {
      const int rA = wr + (m << 4) + fr;
      af[m] = *reinterpret_cast<const bf16x8*>(&At[cur][rA][(fq ^ ((rA >> 4) & 3)) << 3]);
    }
#pragma unroll
    for (int n = 0; n < 4; ++n) {
      const int rB = wc + (n << 4) + fr;
      bfv[n] = *reinterpret_cast<const bf16x8*>(&Bt[cur][rB][(fq ^ ((rB >> 4) & 3)) << 3]);
    }
#pragma unroll
    for (int m = 0; m < 4; ++m)
#pragma unroll
      for (int n = 0; n < 4; ++n)
        acc[m][n] = __builtin_amdgcn_mfma_f32_16x16x32_bf16(af[m], bfv[n], acc[m][n], 0, 0, 0);
    cur ^= 1;
  }
#pragma unroll
  for (int m = 0; m < 4; ++m)
#pragma unroll
    for (int n = 0; n < 4; ++n)
#pragma unroll
      for (int i = 0; i < 4; ++i)
        atomicAdd(&grad[(size_t)(vd0 + wr + (m << 4) + (fq << 2) + i) * 512
                        + kd0 + wc + (n << 4) + fr], acc[m][n][i]);
}

// ---------------------------------------------------------------------------
// C1a: reduce column partials -> colk (512 partials), colv (256 partials)
// ---------------------------------------------------------------------------
__global__ __launch_bounds__(256) void c1a_redcols(
    const float* __restrict__ ckp, const float* __restrict__ cvp,
    float* __restrict__ colk, float* __restrict__ colv)
{
  __shared__ float red[8][32];
  const int t = threadIdx.x, b = blockIdx.x;
  const int mtx = b >> 4;
  const int c = ((b & 15) << 5) + (t & 31);
  const int pg = t >> 5;
  const float* src = mtx ? cvp : ckp;
  const int P = mtx ? 256 : 512;
  float s = 0.f;
  for (int p = pg; p < P; p += 8) s += src[(size_t)p * 512 + c];
  red[pg][t & 31] = s;
  __syncthreads();
  if (pg == 0) {
    float tot = 0.f;
#pragma unroll
    for (int j = 0; j < 8; ++j) tot += red[j][t & 31];
    (mtx ? colv : colk)[c] = tot;
  }
}

// ---------------------------------------------------------------------------
// C1b: gates + loss finalize (1 block)
// ---------------------------------------------------------------------------
__global__ __launch_bounds__(256) void c1b_gates(
    const float* __restrict__ gw, const float* __restrict__ gb,
    const float* __restrict__ colk, const float* __restrict__ colv,
    const float* __restrict__ lossp, float* __restrict__ scal,
    float* __restrict__ outp)
{
  __shared__ float red3[3][4];
  __shared__ float redl[4];
  const int t = threadIdx.x, lane = t & 63, wvi = t >> 6;
  float p[3] = {0.f, 0.f, 0.f};
  for (int j = t; j < 1024; j += 256) {
    const float kv = (j < 512 ? colk[j] : colv[j - 512]) * (1.0f / 32768.0f);
    p[0] += kv * gw[j];
    p[1] += kv * gw[1024 + j];
    p[2] += kv * gw[2048 + j];
  }
  float ls = lossp[t];
#pragma unroll
  for (int o = 32; o; o >>= 1) {
    ls += __shfl_xor(ls, o);
#pragma unroll
    for (int g = 0; g < 3; ++g) p[g] += __shfl_xor(p[g], o);
  }
  if (lane == 0) {
    red3[0][wvi] = p[0]; red3[1][wvi] = p[1]; red3[2][wvi] = p[2];
    redl[wvi] = ls;
  }
  __syncthreads();
  if (t == 0) {
    const float s0 = red3[0][0] + red3[0][1] + red3[0][2] + red3[0][3] + gb[0];
    const float s1 = red3[1][0] + red3[1][1] + red3[1][2] + red3[1][3] + gb[1];
    const float s2 = red3[2][0] + red3[2][1] + red3[2][2] + red3[2][3] + gb[2];
    const float alpha = 1.0f / (1.0f + expf(-s0));
    const float eta   = 1.0f / (1.0f + expf(-s1));
    const float theta = 1.0f / (1.0f + expf(-s2));
    scal[3] = alpha; scal[4] = eta; scal[5] = theta;
    outp[OUT_LOSS] = (redl[0] + redl[1] + redl[2] + redl[3]) * (1.0f / 16777216.0f);
    outp[OUT_ALPHA]     = alpha;
    outp[OUT_ALPHA + 1] = eta;
    outp[OUT_ALPHA + 2] = theta;
  }
}

__device__ __forceinline__ void block_atomic_sumsq(float sq, float* target) {
  __shared__ float red[4];
#pragma unroll
  for (int o = 32; o; o >>= 1) sq += __shfl_xor(sq, o);
  if ((threadIdx.x & 63) == 0) red[threadIdx.x >> 6] = sq;
  __syncthreads();
  if (threadIdx.x == 0) atomicAdd(target, red[0] + red[1] + red[2] + red[3]);
}

// C2: m_raw = eta*S - 0.005*theta*clip(grad*scale); accumulate ||m||^2
__global__ __launch_bounds__(256) void c2_mom(
    const float* __restrict__ grad, const float* __restrict__ S,
    float* scal, float* __restrict__ m_raw)
{
  const float eta = scal[4];
  const float cth = 0.005f * scal[5];
  const int i = ((blockIdx.x << 8) + threadIdx.x) << 2;
  const float4_t g = *reinterpret_cast<const float4_t*>(&grad[i]);
  const float4_t s = *reinterpret_cast<const float4_t*>(&S[i]);
  float4_t m; float sq = 0.f;
#pragma unroll
  for (int j = 0; j < 4; ++j) {
    float gj = g[j] * (2.0f / 16777216.0f);
    gj = fminf(1.0f, fmaxf(-1.0f, gj));
    m[j] = eta * s[j] - cth * gj;
    sq += m[j] * m[j];
  }
  *reinterpret_cast<float4_t*>(&m_raw[i]) = m;
  block_atomic_sumsq(sq, &scal[1]);
}

// C3: clip momentum -> out; w_raw = (1-alpha)*W + m; accumulate ||w||^2
__global__ __launch_bounds__(256) void c3_wt(
    const float* __restrict__ m_raw, const float* __restrict__ memw,
    float* scal, float* __restrict__ w_raw, float* __restrict__ outp)
{
  const float nm = sqrtf(scal[1]);
  const float sm = nm > 5.0f ? 5.0f / (nm + 1e-8f) : 1.0f;
  const float oma = 1.0f - scal[3];
  const int i = ((blockIdx.x << 8) + threadIdx.x) << 2;
  const float4_t mr = *reinterpret_cast<const float4_t*>(&m_raw[i]);
  const float4_t wi = *reinterpret_cast<const float4_t*>(&memw[i]);
  float4_t w; float sq = 0.f;
#pragma unroll
  for (int j = 0; j < 4; ++j) {
    const float m = mr[j] * sm;
    outp[OUT_MOM + i + j] = m;        // OUT_MOM odd -> scalar stores
    w[j] = oma * wi[j] + m;
    sq += w[j] * w[j];
  }
  *reinterpret_cast<float4_t*>(&w_raw[i]) = w;
  block_atomic_sumsq(sq, &scal[2]);
}

// C4: clip weight -> out
__global__ __launch_bounds__(256) void c4_wt(
    const float* __restrict__ w_raw, const float* __restrict__ scal,
    float* __restrict__ outp)
{
  const float nw = sqrtf(scal[2]);
  const float sw = nw > 5.0f ? 5.0f / (nw + 1e-8f) : 1.0f;
  const int i = ((blockIdx.x << 8) + threadIdx.x) << 2;
  const float4_t w = *reinterpret_cast<const float4_t*>(&w_raw[i]);
#pragma unroll
  for (int j = 0; j < 4; ++j)
    outp[OUT_W + i + j] = w[j] * sw;  // OUT_W odd -> scalar stores
}

// ---------------------------------------------------------------------------
extern "C" void kernel_launch(void* const* d_in, const int* in_sizes, int n_in,
                              void* d_out, int out_size, void* d_ws, size_t ws_size,
                              hipStream_t stream)
{
  const float* Kp = (const float*)d_in[0];
  const float* Vp = (const float*)d_in[1];
  const float* Wp = (const float*)d_in[2];
  const float* GW = (const float*)d_in[3];
  const float* GB = (const float*)d_in[4];
  const float* Sp = (const float*)d_in[5];
  float* outp = (float*)d_out;
  char* ws = (char*)d_ws;

  float* grad            = (float*)(ws + OFF_GRAD);
  float* colk_part       = (float*)(ws + OFF_CKP);
  float* colv_part       = (float*)(ws + OFF_CVP);
  float* loss_part       = (float*)(ws + OFF_LOSSP);
  float* colk            = (float*)(ws + OFF_COLK);
  float* colv            = (float*)(ws + OFF_COLV);
  float* scal            = (float*)(ws + OFF_SCAL);
  unsigned short* k16    = (unsigned short*)(ws + OFF_K16);
  unsigned short* w16    = (unsigned short*)(ws + OFF_W16);
  unsigned short* diff16 = (unsigned short*)(ws + OFF_DIFF);
  float* m_raw           = (float*)(ws + OFF_MRAW);
  float* w_raw           = (float*)(ws + OFF_WRAW);

  hipMemsetAsync(ws + OFF_GRAD, 0, 1048576, stream);                  // grad
  hipMemsetAsync(ws + OFF_LOSSP, 0, OFF_SCAL + 64 - OFF_LOSSP, stream); // lossp..scal

  k1_convert<<<528, 256, 0, stream>>>(Kp, Wp, k16, w16, colk_part);
  k2_gemm<<<1024, 256, 0, stream>>>(k16, w16, Vp, outp, diff16, colv_part, loss_part);
  k3_grad<<<512, 256, 0, stream>>>(diff16, k16, grad);
  c1a_redcols<<<32, 256, 0, stream>>>(colk_part, colv_part, colk, colv);
  c1b_gates<<<1, 256, 0, stream>>>(GW, GB, colk, colv, loss_part, scal, outp);
  c2_mom<<<256, 256, 0, stream>>>(grad, Sp, scal, m_raw);
  c3_wt<<<256, 256, 0, stream>>>(m_raw, Wp, scal, w_raw, outp);
  c4_wt<<<256, 256, 0, stream>>>(w_raw, scal, outp);
}